// Round 1
// baseline (542.973 us; speedup 1.0000x reference)
//
#include <hip/hip_runtime.h>
#include <hip/hip_fp16.h>

#define DEVI __device__ __forceinline__

typedef _Float16 f16x8 __attribute__((ext_vector_type(8)));
typedef float f32x4 __attribute__((ext_vector_type(4)));

static DEVI unsigned short f2h_u(float f) {
    _Float16 h = (_Float16)f;
    return __builtin_bit_cast(unsigned short, h);
}
static DEVI float h2f_u(unsigned short u) {
    return (float)__builtin_bit_cast(_Float16, u);
}
static DEVI unsigned pk2(float a, float b) {
    return (unsigned)f2h_u(a) | ((unsigned)f2h_u(b) << 16);
}

// problem constants
// B=32 Q=300 D=256 H=8 C=32 S=8400 levels (80,80)(40,40)(20,20) P=12

// ---------------- kernel 0: weight transpose/convert + combined bias ----------------
// Wvt[n][k] = f16(W_val[k][n])   (256x256)
// Wct[n][k] = f16(n<192 ? W_off[k][n] : W_attn[k][n-192])  (288x256)
// Wot[n][k] = f16(W_out[k][n])   (256x256)
// cbias[0..287] = concat(b_off, b_attn)
__global__ __launch_bounds__(256) void prep_weights(
    const float* __restrict__ W_val, const float* __restrict__ W_off,
    const float* __restrict__ W_attn, const float* __restrict__ W_out,
    const float* __restrict__ b_off, const float* __restrict__ b_attn,
    unsigned short* __restrict__ Wvt, unsigned short* __restrict__ Wct,
    unsigned short* __restrict__ Wot, float* __restrict__ cbias)
{
    int idx = blockIdx.x * 256 + threadIdx.x;
    if (idx < 65536) {
        int n = idx >> 8, k = idx & 255;
        Wvt[idx] = f2h_u(W_val[k * 256 + n]);
    } else if (idx < 65536 + 73728) {
        int j = idx - 65536;
        int n = j >> 8, k = j & 255;
        Wct[j] = f2h_u(n < 192 ? W_off[k * 192 + n] : W_attn[k * 96 + (n - 192)]);
    } else if (idx < 204800) {
        int j = idx - 139264;
        int n = j >> 8, k = j & 255;
        Wot[j] = f2h_u(W_out[k * 256 + n]);
    } else if (idx < 205088) {
        int j = idx - 204800;
        cbias[j] = (j < 192) ? b_off[j] : b_attn[j - 192];
    }
}

// ---------------- templated MFMA GEMM: C = A(f32, Mx256) * Wt^T + bias ----------------
// Wt is pre-transposed f16 [N][256]. BM=64, BK=32, K=256 (8 iters).
// 4 waves, wave w owns rows w*16..w*16+15, all BN cols (NI=BN/16 mfma tiles).
template<int BN, bool OUT_F16>
__global__ __launch_bounds__(256) void gemm_f16(
    const float* __restrict__ A, const unsigned short* __restrict__ Wt,
    const float* __restrict__ bias, void* __restrict__ outp, int ldo)
{
    constexpr int NI  = BN / 16;
    constexpr int LDA = 40;        // ushorts per As row (pad 32->40: 2-way banks only)
    constexpr int LDB = 40;
    constexpr int LDC = BN + 4;    // floats per Cs row (quad offsets 0/16 mod 32)
    constexpr int SM1 = 64 * LDA * 2 + BN * LDB * 2;
    constexpr int SM2 = 64 * LDC * 4;
    constexpr int SMEM = SM1 > SM2 ? SM1 : SM2;
    __shared__ __align__(16) char smem[SMEM];
    unsigned short* As = (unsigned short*)smem;
    unsigned short* Bs = (unsigned short*)(smem + 64 * LDA * 2);
    float* Cs = (float*)smem;

    const int tid  = threadIdx.x;
    const int wave = tid >> 6;
    const int lane = tid & 63;
    const int l15  = lane & 15;
    const int qd   = lane >> 4;
    const int m0   = blockIdx.y * 64;
    const int n0   = blockIdx.x * BN;

    f32x4 acc[NI];
#pragma unroll
    for (int i = 0; i < NI; i++) acc[i] = (f32x4){0.f, 0.f, 0.f, 0.f};

#pragma unroll
    for (int kt = 0; kt < 8; kt++) {
        // stage A tile: 64 rows x 32 f32 -> f16 in LDS
#pragma unroll
        for (int i = 0; i < 2; i++) {
            int f = tid + i * 256;
            int row = f >> 3, c4 = f & 7;
            const float4 v = *(const float4*)(A + (size_t)(m0 + row) * 256 + kt * 32 + c4 * 4);
            uint2 p;
            p.x = pk2(v.x, v.y);
            p.y = pk2(v.z, v.w);
            *(uint2*)&As[row * LDA + c4 * 4] = p;
        }
        // stage B tile: BN rows x 32 f16 (already n-major)
        for (int f = tid; f < BN * 4; f += 256) {
            int row = f >> 2, ch = f & 3;
            uint4 v = *(const uint4*)(Wt + (size_t)(n0 + row) * 256 + kt * 32 + ch * 8);
            *(uint4*)&Bs[row * LDB + ch * 8] = v;
        }
        __syncthreads();
        f16x8 af = *(const f16x8*)&As[(wave * 16 + l15) * LDA + qd * 8];
#pragma unroll
        for (int ni = 0; ni < NI; ni++) {
            f16x8 fb = *(const f16x8*)&Bs[(ni * 16 + l15) * LDB + qd * 8];
            acc[ni] = __builtin_amdgcn_mfma_f32_16x16x32_f16(af, fb, acc[ni], 0, 0, 0);
        }
        __syncthreads();
    }

    // stage C tile to LDS (natural MFMA order), then coalesced global write
#pragma unroll
    for (int ni = 0; ni < NI; ni++) {
#pragma unroll
        for (int r = 0; r < 4; r++) {
            Cs[(wave * 16 + qd * 4 + r) * LDC + ni * 16 + l15] = acc[ni][r];
        }
    }
    __syncthreads();
    for (int f = tid; f < 64 * (BN / 4); f += 256) {
        int row = f / (BN / 4), c4 = f % (BN / 4);
        float4 v = *(const float4*)&Cs[row * LDC + c4 * 4];
        const float4 bb = *(const float4*)(bias + n0 + c4 * 4);
        v.x += bb.x; v.y += bb.y; v.z += bb.z; v.w += bb.w;
        if (OUT_F16) {
            uint2 p;
            p.x = pk2(v.x, v.y);
            p.y = pk2(v.z, v.w);
            *(uint2*)((unsigned short*)outp + (size_t)(m0 + row) * ldo + n0 + c4 * 4) = p;
        } else {
            *(float4*)((float*)outp + (size_t)(m0 + row) * ldo + n0 + c4 * 4) = v;
        }
    }
}

// ---------------- fused softmax + location + bilinear sampling + attn weighting ----------------
// one block per (b,q); phase1: 96 threads = (h,p) compute softmax weight + sampling loc
// phase2: 256 threads = (h,c) accumulate 12 points x 4 taps from f16 value
__global__ __launch_bounds__(256) void sample_attn(
    const float* __restrict__ P, const float* __restrict__ refp,
    const unsigned short* __restrict__ val, float* __restrict__ out_attn)
{
    __shared__ float sLog[8][12];
    __shared__ float sLoc[8][12][3];
    const int row = blockIdx.x;          // b*300 + q
    const int b = row / 300;
    const int tid = threadIdx.x;

    const float4 r4 = *(const float4*)(refp + (size_t)row * 4);

    int h = 0, p = 0;
    float offx = 0.f, offy = 0.f, logit = 0.f;
    if (tid < 96) {
        h = tid / 12;
        p = tid - h * 12;
        const float* Pr = P + (size_t)row * 288;
        offx  = Pr[h * 24 + p * 2];
        offy  = Pr[h * 24 + p * 2 + 1];
        logit = Pr[192 + h * 12 + p];
        sLog[h][p] = logit;
    }
    __syncthreads();
    if (tid < 96) {
        float m = -1e30f;
#pragma unroll
        for (int j = 0; j < 12; j++) m = fmaxf(m, sLog[h][j]);
        float s = 0.f;
#pragma unroll
        for (int j = 0; j < 12; j++) s += expf(sLog[h][j] - m);
        float w = expf(logit - m) / s;
        // loc = ref.xy + off * (1/4) * ref.wh * 0.5 ; pixel = loc*W - 0.5
        sLoc[h][p][0] = r4.x + offx * 0.125f * r4.z;
        sLoc[h][p][1] = r4.y + offy * 0.125f * r4.w;
        sLoc[h][p][2] = w;
    }
    __syncthreads();

    const int hh = tid >> 5, c = tid & 31;
    const unsigned short* vb = val + (size_t)b * 8400 * 256 + hh * 32 + c;
    float acc = 0.f;
#pragma unroll
    for (int p2 = 0; p2 < 12; p2++) {
        const int lvl  = p2 >> 2;
        const int W    = (lvl == 0) ? 80 : ((lvl == 1) ? 40 : 20);
        const int Hh   = W;
        const int loff = (lvl == 0) ? 0 : ((lvl == 1) ? 6400 : 8000);
        const float lx = sLoc[hh][p2][0];
        const float ly = sLoc[hh][p2][1];
        const float w  = sLoc[hh][p2][2];
        const float px = lx * (float)W - 0.5f;
        const float py = ly * (float)Hh - 0.5f;
        const float x0f = floorf(px), y0f = floorf(py);
        const float fx = px - x0f, fy = py - y0f;
        const int x0 = (int)x0f, y0 = (int)y0f;
        const int x1 = x0 + 1, y1 = y0 + 1;
        const float w00 = (1.f - fx) * (1.f - fy);
        const float w10 = fx * (1.f - fy);
        const float w01 = (1.f - fx) * fy;
        const float w11 = fx * fy;
        const bool vx0 = (x0 >= 0) && (x0 < W);
        const bool vx1 = (x1 >= 0) && (x1 < W);
        const bool vy0 = (y0 >= 0) && (y0 < Hh);
        const bool vy1 = (y1 >= 0) && (y1 < Hh);
        const int x0c = min(max(x0, 0), W - 1), x1c = min(max(x1, 0), W - 1);
        const int y0c = min(max(y0, 0), Hh - 1), y1c = min(max(y1, 0), Hh - 1);
        const float v00 = h2f_u(vb[(size_t)(loff + y0c * W + x0c) * 256]);
        const float v10 = h2f_u(vb[(size_t)(loff + y0c * W + x1c) * 256]);
        const float v01 = h2f_u(vb[(size_t)(loff + y1c * W + x0c) * 256]);
        const float v11 = h2f_u(vb[(size_t)(loff + y1c * W + x1c) * 256]);
        float sv = 0.f;
        sv += (vx0 && vy0) ? w00 * v00 : 0.f;
        sv += (vx1 && vy0) ? w10 * v10 : 0.f;
        sv += (vx0 && vy1) ? w01 * v01 : 0.f;
        sv += (vx1 && vy1) ? w11 * v11 : 0.f;
        acc += w * sv;
    }
    out_attn[(size_t)row * 256 + tid] = acc;
}

extern "C" void kernel_launch(void* const* d_in, const int* in_sizes, int n_in,
                              void* d_out, int out_size, void* d_ws, size_t ws_size,
                              hipStream_t stream)
{
    const float* hs     = (const float*)d_in[0];
    const float* enc    = (const float*)d_in[1];
    const float* refp   = (const float*)d_in[2];
    const float* W_off  = (const float*)d_in[3];
    const float* b_off  = (const float*)d_in[4];
    const float* W_attn = (const float*)d_in[5];
    const float* b_attn = (const float*)d_in[6];
    const float* W_val  = (const float*)d_in[7];
    const float* b_val  = (const float*)d_in[8];
    const float* W_out  = (const float*)d_in[9];
    const float* b_out  = (const float*)d_in[10];
    float* outp = (float*)d_out;

    // workspace layout (bytes)
    char* ws = (char*)d_ws;
    unsigned short* val = (unsigned short*)ws;                 // 268800*256*2 = 137,625,600
    float* P            = (float*)(ws + 137625600);            // 9600*288*4   =  11,059,200
    float* oattn        = (float*)(ws + 148684800);            // 9600*256*4   =   9,830,400
    unsigned short* Wvt = (unsigned short*)(ws + 158515200);   // 256*256*2    =     131,072
    unsigned short* Wct = (unsigned short*)(ws + 158646272);   // 288*256*2    =     147,456
    unsigned short* Wot = (unsigned short*)(ws + 158793728);   // 256*256*2    =     131,072
    float* cbias        = (float*)(ws + 158924800);            // 288*4        =       1,152

    prep_weights<<<802, 256, 0, stream>>>(W_val, W_off, W_attn, W_out,
                                          b_off, b_attn, Wvt, Wct, Wot, cbias);
    // proj: (9600x256) @ (256x288) -> P (f32)
    gemm_f16<144, false><<<dim3(2, 150), 256, 0, stream>>>(hs, Wct, cbias, P, 288);
    // value: (268800x256) @ (256x256) -> val (f16)
    gemm_f16<128, true ><<<dim3(2, 4200), 256, 0, stream>>>(enc, Wvt, b_val, val, 256);
    // fused sampling
    sample_attn<<<9600, 256, 0, stream>>>(P, refp, val, oattn);
    // out: (9600x256) @ (256x256) -> d_out (f32)
    gemm_f16<128, false><<<dim3(2, 150), 256, 0, stream>>>(oattn, Wot, b_out, outp, 256);
}